// Round 2
// baseline (316.966 us; speedup 1.0000x reference)
//
#include <hip/hip_runtime.h>
#include <hip/hip_bf16.h>
#include <stdint.h>

#define BS 8
#define TT 4096
#define DI 1024
#define DH 1024
#define DO 1024
#define M1 (BS*TT)      // 32768
#define NC 32           // scan chunks
#define CL (TT/NC)      // 128

typedef __attribute__((ext_vector_type(8))) __bf16 bf16x8;
typedef __attribute__((ext_vector_type(4))) __bf16 bf16x4;
typedef __attribute__((ext_vector_type(4))) float f32x4;

// ---------- transpose + convert: dst[n][k] = (bf16) src[k][n], src is KxN ----------
__global__ void transp_conv_kernel(const float* __restrict__ src, __bf16* __restrict__ dst,
                                   int K, int N) {
    __shared__ float tile[32][33];
    const int tx = threadIdx.x & 31;
    const int ty = threadIdx.x >> 5;   // 0..7
    const int k0 = blockIdx.x * 32;
    const int n0 = blockIdx.y * 32;
    #pragma unroll
    for (int i = 0; i < 32; i += 8)
        tile[ty + i][tx] = src[(size_t)(k0 + ty + i) * N + n0 + tx];
    __syncthreads();
    #pragma unroll
    for (int i = 0; i < 32; i += 8)
        dst[(size_t)(n0 + ty + i) * K + k0 + tx] = (__bf16)tile[tx][ty + i];
}

// ---------- GEMM (m97 structure). FIRST=1: A fp32 (converted in-reg), out bf16.
//            FIRST=0: A bf16, out fp32. B always bf16 [N][K] (pre-transposed). ----------
template<int FIRST>
__global__ __launch_bounds__(256, 2) void gemm_kernel(
    const float* __restrict__ Af, const __bf16* __restrict__ Ah,
    const __bf16* __restrict__ Bt,
    __bf16* __restrict__ Obf, float* __restrict__ Of,
    int M, int N, int K)
{
    __shared__ __align__(16) char smem[(FIRST ? 32768 : 16384) + 16384];
    float*  AsF = (float*)smem;
    __bf16* AsH = (__bf16*)smem;
    __bf16* Bs  = (__bf16*)(smem + (FIRST ? 32768 : 16384));

    const int tid = threadIdx.x;
    const int w = tid >> 6;            // wave 0..3
    const int l = tid & 63;
    const int rowBase = blockIdx.x * 128;
    const int colBase = blockIdx.y * 128;
    const int wm = w >> 1, wn = w & 1; // 2x2 wave grid, 64x64 each
    const int lr = l & 15;
    const int lk = (l >> 4) * 8;

    f32x4 acc[4][4];
    #pragma unroll
    for (int i = 0; i < 4; i++)
        #pragma unroll
        for (int j = 0; j < 4; j++)
            acc[i][j] = (f32x4){0.f, 0.f, 0.f, 0.f};

    // staging: each lane loads 16B; LDS dest = wave-uniform base + lane*16 (HW rule)
    const float*  AgF = Af ? Af + (size_t)(rowBase + w * 4 + (l >> 4)) * K + (l & 15) * 4 : nullptr;
    const __bf16* AgH = Ah ? Ah + (size_t)(rowBase + w * 8 + (l >> 3)) * K + (l & 7) * 8 : nullptr;
    const __bf16* Bg  = Bt + (size_t)(colBase + w * 8 + (l >> 3)) * K + (l & 7) * 8;
    float*  AswF = AsF + w * 4 * 64;   // 4 rows/wave/issue * 64 f32 = 1024B
    __bf16* AswH = AsH + w * 8 * 64;   // 8 rows/wave/issue * 64 bf16 = 1024B
    __bf16* Bsw  = Bs  + w * 8 * 64;

    for (int kt = 0; kt < K; kt += 64) {
        if constexpr (FIRST) {
            #pragma unroll
            for (int i = 0; i < 8; i++)
                __builtin_amdgcn_global_load_lds(
                    (const __attribute__((address_space(1))) void*)(AgF + (size_t)(i * 16) * K + kt),
                    (__attribute__((address_space(3))) void*)(AswF + i * 1024), 16, 0, 0);
        } else {
            #pragma unroll
            for (int i = 0; i < 4; i++)
                __builtin_amdgcn_global_load_lds(
                    (const __attribute__((address_space(1))) void*)(AgH + (size_t)(i * 32) * K + kt),
                    (__attribute__((address_space(3))) void*)(AswH + i * 2048), 16, 0, 0);
        }
        #pragma unroll
        for (int i = 0; i < 4; i++)
            __builtin_amdgcn_global_load_lds(
                (const __attribute__((address_space(1))) void*)(Bg + (size_t)(i * 32) * K + kt),
                (__attribute__((address_space(3))) void*)(Bsw + i * 2048), 16, 0, 0);
        __syncthreads();

        #pragma unroll
        for (int kk = 0; kk < 64; kk += 32) {
            bf16x8 af[4], bfr[4];
            #pragma unroll
            for (int m = 0; m < 4; m++) {
                const int row = wm * 64 + m * 16 + lr;
                if constexpr (FIRST) {
                    f32x4 lo = *(f32x4*)&AsF[row * 64 + kk + lk];
                    f32x4 hi = *(f32x4*)&AsF[row * 64 + kk + lk + 4];
                    bf16x8 t;
                    t[0] = (__bf16)lo[0]; t[1] = (__bf16)lo[1];
                    t[2] = (__bf16)lo[2]; t[3] = (__bf16)lo[3];
                    t[4] = (__bf16)hi[0]; t[5] = (__bf16)hi[1];
                    t[6] = (__bf16)hi[2]; t[7] = (__bf16)hi[3];
                    af[m] = t;
                } else {
                    af[m] = *(bf16x8*)&AsH[row * 64 + kk + lk];
                }
            }
            #pragma unroll
            for (int n = 0; n < 4; n++)
                bfr[n] = *(bf16x8*)&Bs[(wn * 64 + n * 16 + lr) * 64 + kk + lk];
            #pragma unroll
            for (int m = 0; m < 4; m++)
                #pragma unroll
                for (int n = 0; n < 4; n++)
                    acc[m][n] = __builtin_amdgcn_mfma_f32_16x16x32_bf16(af[m], bfr[n], acc[m][n], 0, 0, 0);
        }
        __syncthreads();
    }

    // epilogue: C/D layout col=lane&15, row=(lane>>4)*4+j [m89]
    const int orow = rowBase + wm * 64 + (l >> 4) * 4;
    const int ocol = colBase + wn * 64 + lr;
    #pragma unroll
    for (int m = 0; m < 4; m++)
        #pragma unroll
        for (int n = 0; n < 4; n++)
            #pragma unroll
            for (int j = 0; j < 4; j++) {
                size_t idx = (size_t)(orow + m * 16 + j) * N + ocol + n * 16;
                if constexpr (FIRST) Obf[idx] = (__bf16)acc[m][n][j];
                else                 Of[idx]  = acc[m][n][j];
            }
}

// ---------- scan pass 1: per-chunk local scan (in place, bf16), emit chunk-end E (fp32) ----------
__global__ void scan1_kernel(__bf16* __restrict__ u, const float* __restrict__ a,
                             float* __restrict__ E) {
    int g = blockIdx.x * blockDim.x + threadIdx.x;   // BS*NC*(DH/4) threads
    int c4 = g & 255;
    int rest = g >> 8;
    int k = rest & (NC - 1);
    int b = rest >> 5;
    int ch = c4 * 4;
    f32x4 av = { a[ch], a[ch + 1], a[ch + 2], a[ch + 3] };
    size_t base = ((size_t)(b * TT + k * CL)) * DH + ch;
    f32x4 h = {0.f, 0.f, 0.f, 0.f};
    for (int t = 0; t < CL; t++) {
        size_t idx = base + (size_t)t * DH;
        bf16x4 v = *(bf16x4*)&u[idx];
        h[0] = h[0] * av[0] + (float)v[0];
        h[1] = h[1] * av[1] + (float)v[1];
        h[2] = h[2] * av[2] + (float)v[2];
        h[3] = h[3] * av[3] + (float)v[3];
        bf16x4 o;
        o[0] = (__bf16)h[0]; o[1] = (__bf16)h[1];
        o[2] = (__bf16)h[2]; o[3] = (__bf16)h[3];
        *(bf16x4*)&u[idx] = o;
    }
    *(f32x4*)&E[((size_t)(b * NC + k)) * DH + ch] = h;
}

// ---------- scan pass 2: combine chunk carries (fp32) ----------
__global__ void scan2_kernel(const float* __restrict__ E, const float* __restrict__ a,
                             float* __restrict__ Cc) {
    int g = blockIdx.x * blockDim.x + threadIdx.x;   // BS*DH threads
    int ch = g & (DH - 1);
    int b = g >> 10;
    float av = a[ch];
    float aL = av;
    #pragma unroll
    for (int i = 0; i < 7; i++) aL *= aL;            // a^128
    float carry = 0.f;
    for (int k = 0; k < NC; k++) {
        size_t idx = ((size_t)(b * NC + k)) * DH + ch;
        Cc[idx] = carry;
        carry = aL * carry + E[idx];
    }
}

// ---------- scan pass 3: apply carry, rewrite bf16 in place ----------
__global__ void scan3_kernel(__bf16* __restrict__ u, const float* __restrict__ a,
                             const float* __restrict__ Cc) {
    int g = blockIdx.x * blockDim.x + threadIdx.x;   // BS*NC*(DH/4) threads
    int c4 = g & 255;
    int rest = g >> 8;
    int k = rest & (NC - 1);
    int b = rest >> 5;
    int ch = c4 * 4;
    f32x4 av = { a[ch], a[ch + 1], a[ch + 2], a[ch + 3] };
    f32x4 p = *(const f32x4*)&Cc[((size_t)(b * NC + k)) * DH + ch];
    size_t base = ((size_t)(b * TT + k * CL)) * DH + ch;
    for (int t = 0; t < CL; t++) {
        p[0] *= av[0]; p[1] *= av[1]; p[2] *= av[2]; p[3] *= av[3];
        size_t idx = base + (size_t)t * DH;
        bf16x4 v = *(bf16x4*)&u[idx];
        bf16x4 o;
        o[0] = (__bf16)((float)v[0] + p[0]);
        o[1] = (__bf16)((float)v[1] + p[1]);
        o[2] = (__bf16)((float)v[2] + p[2]);
        o[3] = (__bf16)((float)v[3] + p[3]);
        *(bf16x4*)&u[idx] = o;
    }
}

extern "C" void kernel_launch(void* const* d_in, const int* in_sizes, int n_in,
                              void* d_out, int out_size, void* d_ws, size_t ws_size,
                              hipStream_t stream) {
    const float* x = (const float*)d_in[0];
    const float* a = (const float*)d_in[1];
    const float* b = (const float*)d_in[2];
    const float* c = (const float*)d_in[3];
    float* y = (float*)d_out;

    char* ws = (char*)d_ws;
    size_t off = 0;
    __bf16* u  = (__bf16*)(ws + off); off += (size_t)M1 * DH * 2;        // 64 MiB
    __bf16* bT = (__bf16*)(ws + off); off += (size_t)DI * DH * 2;        // 2 MiB
    __bf16* cT = (__bf16*)(ws + off); off += (size_t)DH * DO * 2;        // 2 MiB
    float*  E  = (float*)(ws + off);  off += (size_t)BS * NC * DH * 4;   // 1 MiB
    float*  Cc = (float*)(ws + off);  off += (size_t)BS * NC * DH * 4;   // 1 MiB
    if (ws_size < off) return;  // fail loudly (wrong output) rather than corrupt memory

    transp_conv_kernel<<<dim3(DI / 32, DH / 32), 256, 0, stream>>>(b, bT, DI, DH);
    transp_conv_kernel<<<dim3(DH / 32, DO / 32), 256, 0, stream>>>(c, cT, DH, DO);
    // u = bf16(x @ b), A staged as fp32 + converted in-register
    gemm_kernel<1><<<dim3(M1 / 128, DH / 128), 256, 0, stream>>>(x, nullptr, bT, u, nullptr, M1, DH, DI);
    // chunked diagonal linear scan over T (in place on u)
    scan1_kernel<<<(BS * NC * (DH / 4)) / 256, 256, 0, stream>>>(u, a, E);
    scan2_kernel<<<(BS * DH) / 256, 256, 0, stream>>>(E, a, Cc);
    scan3_kernel<<<(BS * NC * (DH / 4)) / 256, 256, 0, stream>>>(u, a, Cc);
    // y = hs @ c
    gemm_kernel<0><<<dim3(M1 / 128, DO / 128), 256, 0, stream>>>(nullptr, u, cT, nullptr, y, M1, DO, DH);
}

// Round 5
// 262.985 us; speedup vs baseline: 1.2053x; 1.2053x over previous
//
#include <hip/hip_runtime.h>
#include <hip/hip_bf16.h>
#include <stdint.h>

#define BS 8
#define TT 4096
#define DI 1024
#define DH 1024
#define DO 1024
#define M1 (BS*TT)      // 32768
#define NC 64           // scan chunks
#define CL (TT/NC)      // 64

typedef __attribute__((ext_vector_type(8))) __bf16 bf16x8;
typedef __attribute__((ext_vector_type(4))) __bf16 bf16x4;
typedef __attribute__((ext_vector_type(4))) float f32x4;

// ---------- fp32 -> bf16 flat conversion: 8 elems/thread ----------
__global__ void conv_bf16_kernel(const float* __restrict__ in, __bf16* __restrict__ out, int n8) {
    int i = blockIdx.x * blockDim.x + threadIdx.x;
    int stride = gridDim.x * blockDim.x;
    for (; i < n8; i += stride) {
        f32x4 v0 = *(const f32x4*)&in[(size_t)i * 8];
        f32x4 v1 = *(const f32x4*)&in[(size_t)i * 8 + 4];
        bf16x8 o;
        o[0] = (__bf16)v0[0]; o[1] = (__bf16)v0[1]; o[2] = (__bf16)v0[2]; o[3] = (__bf16)v0[3];
        o[4] = (__bf16)v1[0]; o[5] = (__bf16)v1[1]; o[6] = (__bf16)v1[2]; o[7] = (__bf16)v1[3];
        *(bf16x8*)&out[(size_t)i * 8] = o;
    }
}

// ---------- transpose + convert: dst[n][k] = (bf16) src[k][n], src is KxN ----------
__global__ void transp_conv_kernel(const float* __restrict__ src, __bf16* __restrict__ dst,
                                   int K, int N) {
    __shared__ float tile[32][33];
    const int tx = threadIdx.x & 31;
    const int ty = threadIdx.x >> 5;   // 0..7
    const int k0 = blockIdx.x * 32;
    const int n0 = blockIdx.y * 32;
    #pragma unroll
    for (int i = 0; i < 32; i += 8)
        tile[ty + i][tx] = src[(size_t)(k0 + ty + i) * N + n0 + tx];
    __syncthreads();
    #pragma unroll
    for (int i = 0; i < 32; i += 8)
        dst[(size_t)(n0 + ty + i) * K + k0 + tx] = (__bf16)tile[tx][ty + i];
}

// ---------- bf16 GEMM, m97 structure: C[M][N] = A[M][K] * Bt[N][K]^T ----------
// OUTF32=0: write bf16.  OUTF32=1: write fp32.
template<int OUTF32>
__global__ __launch_bounds__(256, 2) void gemm_bt_kernel(
    const __bf16* __restrict__ A, const __bf16* __restrict__ Bt,
    __bf16* __restrict__ Obf, float* __restrict__ Of,
    int M, int N, int K)
{
    __shared__ __bf16 As[128 * 64];   // row-major [128][64], linear (gload_lds dest)
    __shared__ __bf16 Bs[128 * 64];

    const int tid = threadIdx.x;
    const int w = tid >> 6;            // wave 0..3
    const int l = tid & 63;
    const int rowBase = blockIdx.x * 128;
    const int colBase = blockIdx.y * 128;
    const int wm = w >> 1, wn = w & 1; // 2x2 wave grid, each wave 64x64
    const int lr = l & 15;
    const int lk = (l >> 4) * 8;

    f32x4 acc[4][4];
    #pragma unroll
    for (int i = 0; i < 4; i++)
        #pragma unroll
        for (int j = 0; j < 4; j++)
            acc[i][j] = (f32x4){0.f, 0.f, 0.f, 0.f};

    // staging: lane covers row w*8+(l>>3), col (l&7)*8 (16B); wave-linear LDS dest
    const __bf16* Ag = A  + (size_t)(rowBase + w * 8 + (l >> 3)) * K + (l & 7) * 8;
    const __bf16* Bg = Bt + (size_t)(colBase + w * 8 + (l >> 3)) * K + (l & 7) * 8;
    __bf16* Asw = As + w * 512;
    __bf16* Bsw = Bs + w * 512;

    for (int kt = 0; kt < K; kt += 64) {
        #pragma unroll
        for (int i = 0; i < 4; i++) {
            __builtin_amdgcn_global_load_lds(
                (const __attribute__((address_space(1))) void*)(Ag + (size_t)(i * 32) * K + kt),
                (__attribute__((address_space(3))) void*)(Asw + i * 2048), 16, 0, 0);
            __builtin_amdgcn_global_load_lds(
                (const __attribute__((address_space(1))) void*)(Bg + (size_t)(i * 32) * K + kt),
                (__attribute__((address_space(3))) void*)(Bsw + i * 2048), 16, 0, 0);
        }
        __syncthreads();
        #pragma unroll
        for (int kk = 0; kk < 64; kk += 32) {
            bf16x8 af[4], bfr[4];
            #pragma unroll
            for (int m = 0; m < 4; m++)
                af[m] = *(bf16x8*)&As[(wm * 64 + m * 16 + lr) * 64 + kk + lk];
            #pragma unroll
            for (int n = 0; n < 4; n++)
                bfr[n] = *(bf16x8*)&Bs[(wn * 64 + n * 16 + lr) * 64 + kk + lk];
            #pragma unroll
            for (int m = 0; m < 4; m++)
                #pragma unroll
                for (int n = 0; n < 4; n++)
                    acc[m][n] = __builtin_amdgcn_mfma_f32_16x16x32_bf16(af[m], bfr[n], acc[m][n], 0, 0, 0);
        }
        __syncthreads();
    }

    // epilogue: C/D layout col=lane&15, row=(lane>>4)*4+j [m89]
    const int orow = rowBase + wm * 64 + (l >> 4) * 4;
    const int ocol = colBase + wn * 64 + lr;
    #pragma unroll
    for (int m = 0; m < 4; m++)
        #pragma unroll
        for (int n = 0; n < 4; n++)
            #pragma unroll
            for (int j = 0; j < 4; j++) {
                size_t idx = (size_t)(orow + m * 16 + j) * N + ocol + n * 16;
                if constexpr (OUTF32) Of[idx] = acc[m][n][j];
                else                  Obf[idx] = (__bf16)acc[m][n][j];
            }
}

// ---------- scan pass 1: read-only local scan, emit chunk-end E (fp32) ----------
__global__ void scan1_kernel(const __bf16* __restrict__ u, const float* __restrict__ a,
                             float* __restrict__ E) {
    int g = blockIdx.x * blockDim.x + threadIdx.x;   // BS*NC*(DH/4) threads
    int c4 = g & 255;
    int rest = g >> 8;
    int k = rest & (NC - 1);
    int b = rest >> 6;
    int ch = c4 * 4;
    f32x4 av = { a[ch], a[ch + 1], a[ch + 2], a[ch + 3] };
    size_t base = ((size_t)(b * TT + k * CL)) * DH + ch;
    f32x4 h = {0.f, 0.f, 0.f, 0.f};
    for (int t = 0; t < CL; t++) {
        bf16x4 v = *(const bf16x4*)&u[base + (size_t)t * DH];
        h[0] = h[0] * av[0] + (float)v[0];
        h[1] = h[1] * av[1] + (float)v[1];
        h[2] = h[2] * av[2] + (float)v[2];
        h[3] = h[3] * av[3] + (float)v[3];
    }
    *(f32x4*)&E[((size_t)(b * NC + k)) * DH + ch] = h;
}

// ---------- scan pass 2: combine chunk carries (fp32) ----------
__global__ void scan2_kernel(const float* __restrict__ E, const float* __restrict__ a,
                             float* __restrict__ Cc) {
    int g = blockIdx.x * blockDim.x + threadIdx.x;   // BS*DH threads
    int ch = g & (DH - 1);
    int b = g >> 10;
    float av = a[ch];
    float aL = av;
    #pragma unroll
    for (int i = 0; i < 6; i++) aL *= aL;            // a^64 = a^CL
    float carry = 0.f;
    for (int k = 0; k < NC; k++) {
        size_t idx = ((size_t)(b * NC + k)) * DH + ch;
        Cc[idx] = carry;
        carry = aL * carry + E[idx];
    }
}

// ---------- scan pass 3: recompute local scan + apply carry, write bf16 in place ----------
__global__ void scan3_kernel(__bf16* __restrict__ u, const float* __restrict__ a,
                             const float* __restrict__ Cc) {
    int g = blockIdx.x * blockDim.x + threadIdx.x;   // BS*NC*(DH/4) threads
    int c4 = g & 255;
    int rest = g >> 8;
    int k = rest & (NC - 1);
    int b = rest >> 6;
    int ch = c4 * 4;
    f32x4 av = { a[ch], a[ch + 1], a[ch + 2], a[ch + 3] };
    f32x4 p = *(const f32x4*)&Cc[((size_t)(b * NC + k)) * DH + ch];
    f32x4 h = {0.f, 0.f, 0.f, 0.f};
    size_t base = ((size_t)(b * TT + k * CL)) * DH + ch;
    for (int t = 0; t < CL; t++) {
        size_t idx = base + (size_t)t * DH;
        bf16x4 v = *(bf16x4*)&u[idx];
        h[0] = h[0] * av[0] + (float)v[0];
        h[1] = h[1] * av[1] + (float)v[1];
        h[2] = h[2] * av[2] + (float)v[2];
        h[3] = h[3] * av[3] + (float)v[3];
        p[0] *= av[0]; p[1] *= av[1]; p[2] *= av[2]; p[3] *= av[3];
        bf16x4 o;
        o[0] = (__bf16)(h[0] + p[0]);
        o[1] = (__bf16)(h[1] + p[1]);
        o[2] = (__bf16)(h[2] + p[2]);
        o[3] = (__bf16)(h[3] + p[3]);
        *(bf16x4*)&u[idx] = o;
    }
}

extern "C" void kernel_launch(void* const* d_in, const int* in_sizes, int n_in,
                              void* d_out, int out_size, void* d_ws, size_t ws_size,
                              hipStream_t stream) {
    const float* x = (const float*)d_in[0];
    const float* a = (const float*)d_in[1];
    const float* b = (const float*)d_in[2];
    const float* c = (const float*)d_in[3];
    float* y = (float*)d_out;

    // workspace: 68 MiB (proven safe in round 2)
    char* ws = (char*)d_ws;
    size_t off = 0;
    __bf16* u  = (__bf16*)(ws + off); off += (size_t)M1 * DH * 2;   // 64 MiB
    __bf16* bT = (__bf16*)(ws + off); off += (size_t)DI * DH * 2;   // 2 MiB
    __bf16* cT = (__bf16*)(ws + off); off += (size_t)DH * DO * 2;   // 2 MiB
    if (ws_size < off) return;

    // scratch inside d_out (128 MiB, fully overwritten by final GEMM):
    //   xbf: first 64 MiB; E, Cc: next 4 MiB. All dead before gemm2 writes y.
    __bf16* xbf = (__bf16*)d_out;
    float*  E   = (float*)((char*)d_out + (size_t)M1 * DI * 2);
    float*  Cc  = E + (size_t)BS * NC * DH;

    conv_bf16_kernel<<<2048, 256, 0, stream>>>(x, xbf, (M1 * DI) / 8);
    transp_conv_kernel<<<dim3(DI / 32, DH / 32), 256, 0, stream>>>(b, bT, DI, DH);
    transp_conv_kernel<<<dim3(DH / 32, DO / 32), 256, 0, stream>>>(c, cT, DH, DO);
    // u = bf16(x @ b)
    gemm_bt_kernel<0><<<dim3(M1 / 128, DH / 128), 256, 0, stream>>>(xbf, bT, u, nullptr, M1, DH, DI);
    // chunked diagonal linear scan over T (in place on u)
    scan1_kernel<<<(BS * NC * (DH / 4)) / 256, 256, 0, stream>>>(u, a, E);
    scan2_kernel<<<(BS * DH) / 256, 256, 0, stream>>>(E, a, Cc);
    scan3_kernel<<<(BS * NC * (DH / 4)) / 256, 256, 0, stream>>>(u, a, Cc);
    // y = hs @ c
    gemm_bt_kernel<1><<<dim3(M1 / 128, DO / 128), 256, 0, stream>>>(u, cT, nullptr, y, M1, DO, DH);
}

// Round 6
// 231.098 us; speedup vs baseline: 1.3716x; 1.1380x over previous
//
#include <hip/hip_runtime.h>
#include <hip/hip_bf16.h>
#include <stdint.h>

#define BS 8
#define TT 4096
#define DI 1024
#define DH 1024
#define DO 1024
#define M1 (BS*TT)      // 32768
#define NC 64           // scan chunks
#define CL (TT/NC)      // 64

typedef __attribute__((ext_vector_type(8))) __bf16 bf16x8;
typedef __attribute__((ext_vector_type(4))) __bf16 bf16x4;
typedef __attribute__((ext_vector_type(4))) float f32x4;

// ---------- fp32 -> bf16 flat conversion ----------
__global__ void conv_bf16_kernel(const float* __restrict__ in, __bf16* __restrict__ out, int n8) {
    int i = blockIdx.x * blockDim.x + threadIdx.x;
    int stride = gridDim.x * blockDim.x;
    for (; i < n8; i += stride) {
        f32x4 v0 = *(const f32x4*)&in[(size_t)i * 8];
        f32x4 v1 = *(const f32x4*)&in[(size_t)i * 8 + 4];
        bf16x8 o;
        o[0] = (__bf16)v0[0]; o[1] = (__bf16)v0[1]; o[2] = (__bf16)v0[2]; o[3] = (__bf16)v0[3];
        o[4] = (__bf16)v1[0]; o[5] = (__bf16)v1[1]; o[6] = (__bf16)v1[2]; o[7] = (__bf16)v1[3];
        *(bf16x8*)&out[(size_t)i * 8] = o;
    }
}

// ---------- transpose + convert: dst[n][k] = (bf16) src[k][n] ----------
__global__ void transp_conv_kernel(const float* __restrict__ src, __bf16* __restrict__ dst,
                                   int K, int N) {
    __shared__ float tile[32][33];
    const int tx = threadIdx.x & 31;
    const int ty = threadIdx.x >> 5;
    const int k0 = blockIdx.x * 32;
    const int n0 = blockIdx.y * 32;
    #pragma unroll
    for (int i = 0; i < 32; i += 8)
        tile[ty + i][tx] = src[(size_t)(k0 + ty + i) * N + n0 + tx];
    __syncthreads();
    #pragma unroll
    for (int i = 0; i < 32; i += 8)
        dst[(size_t)(n0 + ty + i) * K + k0 + tx] = (__bf16)tile[tx][ty + i];
}

// ---------- 256x256 8-phase bf16 GEMM (T2+T3+T4+T5): C = A[M][K] * Bt[N][K]^T ----------
// 8 waves (2 row-slots x 4 col-slots). Phase = quadrant (qr,qc) of the 256x256 C tile.
// LDS 128 KiB: A/B x 2 buf x 2 half (each half-tile 128 rows x 64 k bf16, XOR-swizzled).
// Counted vmcnt(4) at phases 4 & 8; raw s_barrier (no vmcnt drain); setprio around MFMA.
template<int OUTF32>
__global__ __launch_bounds__(512, 2) void gemm256_kernel(
    const __bf16* __restrict__ A, const __bf16* __restrict__ Bt,
    __bf16* __restrict__ Obf, float* __restrict__ Of,
    int M, int N, int K)
{
    __shared__ __bf16 lds[65536];   // A slots [0,32768), B slots [32768,65536)
    const int tid = threadIdx.x;
    const int wv = tid >> 6;          // 0..7
    const int l  = tid & 63;
    const int sr = wv >> 2;           // row slot 0..1
    const int sc = wv & 3;            // col slot 0..3
    const int lr = l & 15;
    const int lk = (l >> 4) * 8;
    const int xsw = (lr & 7) * 8;                 // read-side swizzle (elems)
    const int ak0 = lk ^ xsw, ak1 = (32 + lk) ^ xsw;
    const int rowBase = blockIdx.x * 256;
    const int colBase = blockIdx.y * 256;
    const int aOff = (sr * 64 + lr) * 64;         // A frag row base (elems, within half slot)
    const int bOff = (sc * 32 + lr) * 64;
    const int csw = ((l & 7) ^ (l >> 3)) * 8;     // source-side pre-swizzle (elems)
    const __bf16* aSrc0 = A  + (size_t)(rowBase + wv * 16 + (l >> 3)) * K + csw;
    const __bf16* bSrc0 = Bt + (size_t)(colBase + wv * 16 + (l >> 3)) * K + csw;

    f32x4 acc[2][2][4][2];
    #pragma unroll
    for (int a0 = 0; a0 < 2; a0++)
        #pragma unroll
        for (int b0 = 0; b0 < 2; b0++)
            #pragma unroll
            for (int m = 0; m < 4; m++)
                #pragma unroll
                for (int n = 0; n < 2; n++)
                    acc[a0][b0][m][n] = (f32x4){0.f, 0.f, 0.f, 0.f};

    bf16x8 aF[4][2], bF[2][2];

#define GLD(s, d) __builtin_amdgcn_global_load_lds( \
        (const __attribute__((address_space(1))) void*)(s), \
        (__attribute__((address_space(3))) void*)(d), 16, 0, 0)
// stage half-tile (128 rows x 64 k): this wave's 16 rows, 2 issues of 8 rows
#define STAGE_A(buf, half, ktE) do { \
        const __bf16* s_ = aSrc0 + (size_t)(half) * 128 * K + (ktE); \
        __bf16* d_ = &lds[((buf) * 2 + (half)) * 8192 + wv * 1024]; \
        GLD(s_, d_); GLD(s_ + (size_t)8 * K, d_ + 512); } while (0)
#define STAGE_B(buf, half, ktE) do { \
        const __bf16* s_ = bSrc0 + (size_t)(half) * 128 * K + (ktE); \
        __bf16* d_ = &lds[32768 + ((buf) * 2 + (half)) * 8192 + wv * 1024]; \
        GLD(s_, d_); GLD(s_ + (size_t)8 * K, d_ + 512); } while (0)
#define LOADA(buf, qr) do { \
        const __bf16* Ab_ = &lds[((buf) * 2 + (qr)) * 8192 + aOff]; \
        _Pragma("unroll") \
        for (int m = 0; m < 4; m++) { \
            aF[m][0] = *(const bf16x8*)&Ab_[m * 1024 + ak0]; \
            aF[m][1] = *(const bf16x8*)&Ab_[m * 1024 + ak1]; } } while (0)
#define LOADB(buf, qc) do { \
        const __bf16* Bb_ = &lds[32768 + ((buf) * 2 + (qc)) * 8192 + bOff]; \
        _Pragma("unroll") \
        for (int n = 0; n < 2; n++) { \
            bF[n][0] = *(const bf16x8*)&Bb_[n * 1024 + ak0]; \
            bF[n][1] = *(const bf16x8*)&Bb_[n * 1024 + ak1]; } } while (0)
#define MM(qr, qc) do { \
        __builtin_amdgcn_s_setprio(1); \
        _Pragma("unroll") \
        for (int m = 0; m < 4; m++) \
            _Pragma("unroll") \
            for (int n = 0; n < 2; n++) { \
                acc[qr][qc][m][n] = __builtin_amdgcn_mfma_f32_16x16x32_bf16(aF[m][0], bF[n][0], acc[qr][qc][m][n], 0, 0, 0); \
                acc[qr][qc][m][n] = __builtin_amdgcn_mfma_f32_16x16x32_bf16(aF[m][1], bF[n][1], acc[qr][qc][m][n], 0, 0, 0); } \
        __builtin_amdgcn_s_setprio(0); } while (0)
#define PHEND() do { __builtin_amdgcn_sched_barrier(0); __builtin_amdgcn_s_barrier(); } while (0)
#define PHEND_W(cond) do { __builtin_amdgcn_sched_barrier(0); \
        if (cond) { asm volatile("s_waitcnt vmcnt(0)" ::: "memory"); } \
        else      { asm volatile("s_waitcnt vmcnt(4)" ::: "memory"); } \
        __builtin_amdgcn_s_barrier(); } while (0)

    const int NIT = K >> 7;   // 2 K-tiles (of 64) per iteration

    // prologue: stage K-tile 0 -> buf0, K-tile 1 -> buf1; wait K-tile 0 (leave 8 in flight)
    STAGE_A(0, 0, 0); STAGE_A(0, 1, 0); STAGE_B(0, 0, 0); STAGE_B(0, 1, 0);
    STAGE_A(1, 0, 64); STAGE_A(1, 1, 64); STAGE_B(1, 0, 64); STAGE_B(1, 1, 64);
    asm volatile("s_waitcnt vmcnt(8)" ::: "memory");
    __builtin_amdgcn_s_barrier();

    for (int it = 0; it < NIT; ++it) {
        const int ktOdd  = (2 * it + 1) * 64;   // this iter's odd K-tile (-> buf1 Ah1/Bh1)
        const int ktEv2  = (2 * it + 2) * 64;   // next even K-tile (-> buf0)
        const int ktOdd2 = (2 * it + 3) * 64;   // next odd K-tile (-> buf1 Bh0/Ah0)
        const bool last = (it == NIT - 1);
        // P1: Q(0,0) buf0
        LOADA(0, 0); LOADB(0, 0);
        if (it > 0) STAGE_A(1, 1, ktOdd);
        __builtin_amdgcn_s_barrier();
        MM(0, 0); PHEND();
        // P2: Q(1,0) buf0 (reuse bF)
        LOADA(0, 1);
        if (it > 0) STAGE_B(1, 1, ktOdd);
        __builtin_amdgcn_s_barrier();
        MM(1, 0); PHEND();
        // P3: Q(0,1) buf0
        LOADA(0, 0); LOADB(0, 1);
        if (!last) STAGE_B(0, 0, ktEv2);
        __builtin_amdgcn_s_barrier();
        MM(0, 1); PHEND();
        // P4: Q(1,1) buf0  + group wait (K-tile 2it+1 resident after this)
        LOADA(0, 1);
        if (!last) STAGE_A(0, 0, ktEv2);
        __builtin_amdgcn_s_barrier();
        MM(1, 1); PHEND_W(last);
        // P5: Q(0,0) buf1
        LOADA(1, 0); LOADB(1, 0);
        if (!last) STAGE_A(0, 1, ktEv2);
        __builtin_amdgcn_s_barrier();
        MM(0, 0); PHEND();
        // P6: Q(1,0) buf1
        LOADA(1, 1);
        if (!last) STAGE_B(0, 1, ktEv2);
        __builtin_amdgcn_s_barrier();
        MM(1, 0); PHEND();
        // P7: Q(0,1) buf1
        LOADA(1, 0); LOADB(1, 1);
        if (!last) STAGE_B(1, 0, ktOdd2);
        __builtin_amdgcn_s_barrier();
        MM(0, 1); PHEND();
        // P8: Q(1,1) buf1 + group wait (K-tile 2it+2 resident after this)
        LOADA(1, 1);
        if (!last) STAGE_A(1, 0, ktOdd2);
        __builtin_amdgcn_s_barrier();
        MM(1, 1); PHEND_W(last);
    }

    // epilogue: C/D layout col=lane&15, row=(lane>>4)*4+j [m89]
    #pragma unroll
    for (int qr = 0; qr < 2; qr++)
        #pragma unroll
        for (int qc = 0; qc < 2; qc++)
            #pragma unroll
            for (int m = 0; m < 4; m++)
                #pragma unroll
                for (int n = 0; n < 2; n++)
                    #pragma unroll
                    for (int j = 0; j < 4; j++) {
                        int row = rowBase + qr * 128 + sr * 64 + m * 16 + (l >> 4) * 4 + j;
                        int col = colBase + qc * 128 + sc * 32 + n * 16 + lr;
                        size_t idx = (size_t)row * N + col;
                        if constexpr (OUTF32) Of[idx] = acc[qr][qc][m][n][j];
                        else                  Obf[idx] = (__bf16)acc[qr][qc][m][n][j];
                    }
#undef GLD
#undef STAGE_A
#undef STAGE_B
#undef LOADA
#undef LOADB
#undef MM
#undef PHEND
#undef PHEND_W
}

// ---------- scan pass 1: read-only local scan, emit chunk-end E (fp32) ----------
__global__ void scan1_kernel(const __bf16* __restrict__ u, const float* __restrict__ a,
                             float* __restrict__ E) {
    int g = blockIdx.x * blockDim.x + threadIdx.x;
    int c4 = g & 255;
    int rest = g >> 8;
    int k = rest & (NC - 1);
    int b = rest >> 6;
    int ch = c4 * 4;
    f32x4 av = { a[ch], a[ch + 1], a[ch + 2], a[ch + 3] };
    size_t base = ((size_t)(b * TT + k * CL)) * DH + ch;
    f32x4 h = {0.f, 0.f, 0.f, 0.f};
    for (int t = 0; t < CL; t++) {
        bf16x4 v = *(const bf16x4*)&u[base + (size_t)t * DH];
        h[0] = h[0] * av[0] + (float)v[0];
        h[1] = h[1] * av[1] + (float)v[1];
        h[2] = h[2] * av[2] + (float)v[2];
        h[3] = h[3] * av[3] + (float)v[3];
    }
    *(f32x4*)&E[((size_t)(b * NC + k)) * DH + ch] = h;
}

// ---------- scan pass 2: combine chunk carries ----------
__global__ void scan2_kernel(const float* __restrict__ E, const float* __restrict__ a,
                             float* __restrict__ Cc) {
    int g = blockIdx.x * blockDim.x + threadIdx.x;
    int ch = g & (DH - 1);
    int b = g >> 10;
    float av = a[ch];
    float aL = av;
    #pragma unroll
    for (int i = 0; i < 6; i++) aL *= aL;            // a^64 = a^CL
    float carry = 0.f;
    for (int k = 0; k < NC; k++) {
        size_t idx = ((size_t)(b * NC + k)) * DH + ch;
        Cc[idx] = carry;
        carry = aL * carry + E[idx];
    }
}

// ---------- scan pass 3: recompute local scan + apply carry, write bf16 in place ----------
__global__ void scan3_kernel(__bf16* __restrict__ u, const float* __restrict__ a,
                             const float* __restrict__ Cc) {
    int g = blockIdx.x * blockDim.x + threadIdx.x;
    int c4 = g & 255;
    int rest = g >> 8;
    int k = rest & (NC - 1);
    int b = rest >> 6;
    int ch = c4 * 4;
    f32x4 av = { a[ch], a[ch + 1], a[ch + 2], a[ch + 3] };
    f32x4 p = *(const f32x4*)&Cc[((size_t)(b * NC + k)) * DH + ch];
    f32x4 h = {0.f, 0.f, 0.f, 0.f};
    size_t base = ((size_t)(b * TT + k * CL)) * DH + ch;
    for (int t = 0; t < CL; t++) {
        size_t idx = base + (size_t)t * DH;
        bf16x4 v = *(bf16x4*)&u[idx];
        h[0] = h[0] * av[0] + (float)v[0];
        h[1] = h[1] * av[1] + (float)v[1];
        h[2] = h[2] * av[2] + (float)v[2];
        h[3] = h[3] * av[3] + (float)v[3];
        p[0] *= av[0]; p[1] *= av[1]; p[2] *= av[2]; p[3] *= av[3];
        bf16x4 o;
        o[0] = (__bf16)(h[0] + p[0]);
        o[1] = (__bf16)(h[1] + p[1]);
        o[2] = (__bf16)(h[2] + p[2]);
        o[3] = (__bf16)(h[3] + p[3]);
        *(bf16x4*)&u[idx] = o;
    }
}

extern "C" void kernel_launch(void* const* d_in, const int* in_sizes, int n_in,
                              void* d_out, int out_size, void* d_ws, size_t ws_size,
                              hipStream_t stream) {
    const float* x = (const float*)d_in[0];
    const float* a = (const float*)d_in[1];
    const float* b = (const float*)d_in[2];
    const float* c = (const float*)d_in[3];
    float* y = (float*)d_out;

    // workspace: 68 MiB (proven safe)
    char* ws = (char*)d_ws;
    size_t off = 0;
    __bf16* u  = (__bf16*)(ws + off); off += (size_t)M1 * DH * 2;   // 64 MiB
    __bf16* bT = (__bf16*)(ws + off); off += (size_t)DI * DH * 2;   // 2 MiB
    __bf16* cT = (__bf16*)(ws + off); off += (size_t)DH * DO * 2;   // 2 MiB
    if (ws_size < off) return;

    // scratch inside d_out (dead before gemm2 writes y)
    __bf16* xbf = (__bf16*)d_out;
    float*  E   = (float*)((char*)d_out + (size_t)M1 * DI * 2);
    float*  Cc  = E + (size_t)BS * NC * DH;

    conv_bf16_kernel<<<2048, 256, 0, stream>>>(x, xbf, (M1 * DI) / 8);
    transp_conv_kernel<<<dim3(DI / 32, DH / 32), 256, 0, stream>>>(b, bT, DI, DH);
    transp_conv_kernel<<<dim3(DH / 32, DO / 32), 256, 0, stream>>>(c, cT, DH, DO);
    // u = bf16(x @ b)
    gemm256_kernel<0><<<dim3(M1 / 256, DH / 256), 512, 0, stream>>>(xbf, bT, u, nullptr, M1, DH, DI);
    // chunked diagonal linear scan over T (in place on u)
    scan1_kernel<<<(BS * NC * (DH / 4)) / 256, 256, 0, stream>>>(u, a, E);
    scan2_kernel<<<(BS * DH) / 256, 256, 0, stream>>>(E, a, Cc);
    scan3_kernel<<<(BS * NC * (DH / 4)) / 256, 256, 0, stream>>>(u, a, Cc);
    // y = hs @ c
    gemm256_kernel<1><<<dim3(M1 / 256, DO / 256), 512, 0, stream>>>(u, cT, nullptr, y, M1, DO, DH);
}

// Round 7
// 225.676 us; speedup vs baseline: 1.4045x; 1.0240x over previous
//
#include <hip/hip_runtime.h>
#include <hip/hip_bf16.h>
#include <stdint.h>

#define BS 8
#define TT 4096
#define DI 1024
#define DH 1024
#define DO 1024
#define M1 (BS*TT)      // 32768
#define NC 64           // scan chunks
#define CL (TT/NC)      // 64

typedef __attribute__((ext_vector_type(8))) __bf16 bf16x8;
typedef __attribute__((ext_vector_type(4))) __bf16 bf16x4;
typedef __attribute__((ext_vector_type(4))) float f32x4;

// ---------- fp32 -> bf16 flat conversion ----------
__global__ void conv_bf16_kernel(const float* __restrict__ in, __bf16* __restrict__ out, int n8) {
    int i = blockIdx.x * blockDim.x + threadIdx.x;
    int stride = gridDim.x * blockDim.x;
    for (; i < n8; i += stride) {
        f32x4 v0 = *(const f32x4*)&in[(size_t)i * 8];
        f32x4 v1 = *(const f32x4*)&in[(size_t)i * 8 + 4];
        bf16x8 o;
        o[0] = (__bf16)v0[0]; o[1] = (__bf16)v0[1]; o[2] = (__bf16)v0[2]; o[3] = (__bf16)v0[3];
        o[4] = (__bf16)v1[0]; o[5] = (__bf16)v1[1]; o[6] = (__bf16)v1[2]; o[7] = (__bf16)v1[3];
        *(bf16x8*)&out[(size_t)i * 8] = o;
    }
}

// ---------- transpose + convert: dst[n][k] = (bf16) src[k][n] ----------
__global__ void transp_conv_kernel(const float* __restrict__ src, __bf16* __restrict__ dst,
                                   int K, int N) {
    __shared__ float tile[32][33];
    const int tx = threadIdx.x & 31;
    const int ty = threadIdx.x >> 5;
    const int k0 = blockIdx.x * 32;
    const int n0 = blockIdx.y * 32;
    #pragma unroll
    for (int i = 0; i < 32; i += 8)
        tile[ty + i][tx] = src[(size_t)(k0 + ty + i) * N + n0 + tx];
    __syncthreads();
    #pragma unroll
    for (int i = 0; i < 32; i += 8)
        dst[(size_t)(n0 + ty + i) * K + k0 + tx] = (__bf16)tile[tx][ty + i];
}

// ---------- 256x256 8-phase bf16 GEMM (T2+T3+T4+T5): C = A[M][K] * Bt[N][K]^T ----------
// 8 waves (2 row-slots x 4 col-slots). Snake quadrant order (0,0)->(1,0)->(1,1)->(0,1)
// with BOTH A-quadrant fragment sets held in registers: per-group ds_reads 12/8/4/0.
// LDS 128 KiB: A/B x 2 buf x 2 half (half-tile 128x64 bf16, XOR-swizzled both sides).
// Counted vmcnt(4) at phases 4 & 8; raw s_barrier; setprio around MFMA clusters.
template<int OUTF32>
__global__ __launch_bounds__(512, 2) void gemm256_kernel(
    const __bf16* __restrict__ A, const __bf16* __restrict__ Bt,
    __bf16* __restrict__ Obf, float* __restrict__ Of,
    int M, int N, int K)
{
    __shared__ __bf16 lds[65536];   // A slots [0,32768), B slots [32768,65536)
    const int tid = threadIdx.x;
    const int wv = tid >> 6;          // 0..7
    const int l  = tid & 63;
    const int sr = wv >> 2;           // row slot 0..1
    const int sc = wv & 3;            // col slot 0..3
    const int lr = l & 15;
    const int lk = (l >> 4) * 8;
    const int xsw = (lr & 7) * 8;                 // read-side swizzle (elems)
    const int ak0 = lk ^ xsw, ak1 = (32 + lk) ^ xsw;
    const int rowBase = blockIdx.x * 256;
    const int colBase = blockIdx.y * 256;
    const int aOff = (sr * 64 + lr) * 64;         // A frag row base (elems, within half slot)
    const int bOff = (sc * 32 + lr) * 64;
    const int csw = ((l & 7) ^ (l >> 3)) * 8;     // source-side pre-swizzle (elems)
    const __bf16* aSrc0 = A  + (size_t)(rowBase + wv * 16 + (l >> 3)) * K + csw;
    const __bf16* bSrc0 = Bt + (size_t)(colBase + wv * 16 + (l >> 3)) * K + csw;

    f32x4 acc[2][2][4][2];
    #pragma unroll
    for (int a0 = 0; a0 < 2; a0++)
        #pragma unroll
        for (int b0 = 0; b0 < 2; b0++)
            #pragma unroll
            for (int m = 0; m < 4; m++)
                #pragma unroll
                for (int n = 0; n < 2; n++)
                    acc[a0][b0][m][n] = (f32x4){0.f, 0.f, 0.f, 0.f};

    bf16x8 aF0[4][2], aF1[4][2], bF[2][2];

#define GLD(s, d) __builtin_amdgcn_global_load_lds( \
        (const __attribute__((address_space(1))) void*)(s), \
        (__attribute__((address_space(3))) void*)(d), 16, 0, 0)
#define STAGE_A(buf, half, ktE) do { \
        const __bf16* s_ = aSrc0 + (size_t)(half) * 128 * K + (ktE); \
        __bf16* d_ = &lds[((buf) * 2 + (half)) * 8192 + wv * 1024]; \
        GLD(s_, d_); GLD(s_ + (size_t)8 * K, d_ + 512); } while (0)
#define STAGE_B(buf, half, ktE) do { \
        const __bf16* s_ = bSrc0 + (size_t)(half) * 128 * K + (ktE); \
        __bf16* d_ = &lds[32768 + ((buf) * 2 + (half)) * 8192 + wv * 1024]; \
        GLD(s_, d_); GLD(s_ + (size_t)8 * K, d_ + 512); } while (0)
#define LOADA(buf, qr, AF) do { \
        const __bf16* Ab_ = &lds[((buf) * 2 + (qr)) * 8192 + aOff]; \
        _Pragma("unroll") \
        for (int m = 0; m < 4; m++) { \
            AF[m][0] = *(const bf16x8*)&Ab_[m * 1024 + ak0]; \
            AF[m][1] = *(const bf16x8*)&Ab_[m * 1024 + ak1]; } } while (0)
#define LOADB(buf, qc) do { \
        const __bf16* Bb_ = &lds[32768 + ((buf) * 2 + (qc)) * 8192 + bOff]; \
        _Pragma("unroll") \
        for (int n = 0; n < 2; n++) { \
            bF[n][0] = *(const bf16x8*)&Bb_[n * 1024 + ak0]; \
            bF[n][1] = *(const bf16x8*)&Bb_[n * 1024 + ak1]; } } while (0)
#define MMQ(qr, qc, AF) do { \
        __builtin_amdgcn_s_setprio(1); \
        _Pragma("unroll") \
        for (int m = 0; m < 4; m++) \
            _Pragma("unroll") \
            for (int n = 0; n < 2; n++) { \
                acc[qr][qc][m][n] = __builtin_amdgcn_mfma_f32_16x16x32_bf16(AF[m][0], bF[n][0], acc[qr][qc][m][n], 0, 0, 0); \
                acc[qr][qc][m][n] = __builtin_amdgcn_mfma_f32_16x16x32_bf16(AF[m][1], bF[n][1], acc[qr][qc][m][n], 0, 0, 0); } \
        __builtin_amdgcn_s_setprio(0); } while (0)
// phase-start: pin loads above barrier; all-waves sync; drain own ds_reads; pin MFMA below
#define PH_BAR() do { __builtin_amdgcn_sched_barrier(0); __builtin_amdgcn_s_barrier(); \
        asm volatile("s_waitcnt lgkmcnt(0)" ::: "memory"); \
        __builtin_amdgcn_sched_barrier(0); } while (0)
#define PHEND() do { __builtin_amdgcn_sched_barrier(0); __builtin_amdgcn_s_barrier(); } while (0)
#define PHEND_W(cond) do { __builtin_amdgcn_sched_barrier(0); \
        if (cond) { asm volatile("s_waitcnt vmcnt(0)" ::: "memory"); } \
        else      { asm volatile("s_waitcnt vmcnt(4)" ::: "memory"); } \
        __builtin_amdgcn_s_barrier(); } while (0)

    const int NIT = K >> 7;   // 2 K-tiles (of 64) per iteration

    // prologue: stage K-tile 0 -> buf0, K-tile 1 -> buf1; wait K-tile 0 (leave 8 in flight)
    STAGE_A(0, 0, 0); STAGE_A(0, 1, 0); STAGE_B(0, 0, 0); STAGE_B(0, 1, 0);
    STAGE_A(1, 0, 64); STAGE_A(1, 1, 64); STAGE_B(1, 0, 64); STAGE_B(1, 1, 64);
    asm volatile("s_waitcnt vmcnt(8)" ::: "memory");
    __builtin_amdgcn_s_barrier();

    for (int it = 0; it < NIT; ++it) {
        const int ktOdd  = (2 * it + 1) * 64;   // this iter's odd K-tile (buf1 half1 fill)
        const int ktEv2  = (2 * it + 2) * 64;   // next even K-tile (buf0)
        const int ktOdd2 = (2 * it + 3) * 64;   // next odd K-tile (buf1 half0 fill)
        const bool last = (it == NIT - 1);
        // P1: Q(0,0) buf0 — loads A0 (8) + B0 (4)
        LOADA(0, 0, aF0); LOADB(0, 0);
        if (it > 0) STAGE_A(1, 1, ktOdd);
        PH_BAR(); MMQ(0, 0, aF0); PHEND();
        // P2: Q(1,0) buf0 — loads A1 (8), reuse bF
        LOADA(0, 1, aF1);
        if (it > 0) STAGE_B(1, 1, ktOdd);
        PH_BAR(); MMQ(1, 0, aF1); PHEND();
        // P3: Q(1,1) buf0 — loads B1 (4), reuse aF1
        LOADB(0, 1);
        if (!last) STAGE_B(0, 0, ktEv2);
        PH_BAR(); MMQ(1, 1, aF1); PHEND();
        // P4: Q(0,1) buf0 — no LDS reads; group wait (K-tile 2it+1 resident after this)
        if (!last) STAGE_A(0, 0, ktEv2);
        PH_BAR(); MMQ(0, 1, aF0); PHEND_W(last);
        // P5: Q(0,0) buf1
        LOADA(1, 0, aF0); LOADB(1, 0);
        if (!last) STAGE_A(0, 1, ktEv2);
        PH_BAR(); MMQ(0, 0, aF0); PHEND();
        // P6: Q(1,0) buf1
        LOADA(1, 1, aF1);
        if (!last) STAGE_B(0, 1, ktEv2);
        PH_BAR(); MMQ(1, 0, aF1); PHEND();
        // P7: Q(1,1) buf1
        LOADB(1, 1);
        if (!last) STAGE_B(1, 0, ktOdd2);
        PH_BAR(); MMQ(1, 1, aF1); PHEND();
        // P8: Q(0,1) buf1 — no LDS reads; group wait (K-tile 2it+2 resident after this)
        if (!last) STAGE_A(1, 0, ktOdd2);
        PH_BAR(); MMQ(0, 1, aF0); PHEND_W(last);
    }

    // epilogue: C/D layout col=lane&15, row=(lane>>4)*4+j [m89]
    #pragma unroll
    for (int qr = 0; qr < 2; qr++)
        #pragma unroll
        for (int qc = 0; qc < 2; qc++)
            #pragma unroll
            for (int m = 0; m < 4; m++)
                #pragma unroll
                for (int n = 0; n < 2; n++)
                    #pragma unroll
                    for (int j = 0; j < 4; j++) {
                        int row = rowBase + qr * 128 + sr * 64 + m * 16 + (l >> 4) * 4 + j;
                        int col = colBase + qc * 128 + sc * 32 + n * 16 + lr;
                        size_t idx = (size_t)row * N + col;
                        if constexpr (OUTF32) Of[idx] = acc[qr][qc][m][n][j];
                        else                  Obf[idx] = (__bf16)acc[qr][qc][m][n][j];
                    }
#undef GLD
#undef STAGE_A
#undef STAGE_B
#undef LOADA
#undef LOADB
#undef MMQ
#undef PH_BAR
#undef PHEND
#undef PHEND_W
}

// ---------- scan pass 1: read-only local scan, emit chunk-end E (fp32) ----------
__global__ void scan1_kernel(const __bf16* __restrict__ u, const float* __restrict__ a,
                             float* __restrict__ E) {
    int g = blockIdx.x * blockDim.x + threadIdx.x;
    int c4 = g & 255;
    int rest = g >> 8;
    int k = rest & (NC - 1);
    int b = rest >> 6;
    int ch = c4 * 4;
    f32x4 av = { a[ch], a[ch + 1], a[ch + 2], a[ch + 3] };
    size_t base = ((size_t)(b * TT + k * CL)) * DH + ch;
    f32x4 h = {0.f, 0.f, 0.f, 0.f};
    for (int t = 0; t < CL; t++) {
        bf16x4 v = *(const bf16x4*)&u[base + (size_t)t * DH];
        h[0] = h[0] * av[0] + (float)v[0];
        h[1] = h[1] * av[1] + (float)v[1];
        h[2] = h[2] * av[2] + (float)v[2];
        h[3] = h[3] * av[3] + (float)v[3];
    }
    *(f32x4*)&E[((size_t)(b * NC + k)) * DH + ch] = h;
}

// ---------- scan pass 2: combine chunk carries ----------
__global__ void scan2_kernel(const float* __restrict__ E, const float* __restrict__ a,
                             float* __restrict__ Cc) {
    int g = blockIdx.x * blockDim.x + threadIdx.x;
    int ch = g & (DH - 1);
    int b = g >> 10;
    float av = a[ch];
    float aL = av;
    #pragma unroll
    for (int i = 0; i < 6; i++) aL *= aL;            // a^64 = a^CL
    float carry = 0.f;
    for (int k = 0; k < NC; k++) {
        size_t idx = ((size_t)(b * NC + k)) * DH + ch;
        Cc[idx] = carry;
        carry = aL * carry + E[idx];
    }
}

// ---------- scan pass 3: recompute local scan + apply carry, write bf16 in place ----------
__global__ void scan3_kernel(__bf16* __restrict__ u, const float* __restrict__ a,
                             const float* __restrict__ Cc) {
    int g = blockIdx.x * blockDim.x + threadIdx.x;
    int c4 = g & 255;
    int rest = g >> 8;
    int k = rest & (NC - 1);
    int b = rest >> 6;
    int ch = c4 * 4;
    f32x4 av = { a[ch], a[ch + 1], a[ch + 2], a[ch + 3] };
    f32x4 p = *(const f32x4*)&Cc[((size_t)(b * NC + k)) * DH + ch];
    f32x4 h = {0.f, 0.f, 0.f, 0.f};
    size_t base = ((size_t)(b * TT + k * CL)) * DH + ch;
    for (int t = 0; t < CL; t++) {
        size_t idx = base + (size_t)t * DH;
        bf16x4 v = *(bf16x4*)&u[idx];
        h[0] = h[0] * av[0] + (float)v[0];
        h[1] = h[1] * av[1] + (float)v[1];
        h[2] = h[2] * av[2] + (float)v[2];
        h[3] = h[3] * av[3] + (float)v[3];
        p[0] *= av[0]; p[1] *= av[1]; p[2] *= av[2]; p[3] *= av[3];
        bf16x4 o;
        o[0] = (__bf16)(h[0] + p[0]);
        o[1] = (__bf16)(h[1] + p[1]);
        o[2] = (__bf16)(h[2] + p[2]);
        o[3] = (__bf16)(h[3] + p[3]);
        *(bf16x4*)&u[idx] = o;
    }
}

extern "C" void kernel_launch(void* const* d_in, const int* in_sizes, int n_in,
                              void* d_out, int out_size, void* d_ws, size_t ws_size,
                              hipStream_t stream) {
    const float* x = (const float*)d_in[0];
    const float* a = (const float*)d_in[1];
    const float* b = (const float*)d_in[2];
    const float* c = (const float*)d_in[3];
    float* y = (float*)d_out;

    // workspace: 68 MiB (proven safe)
    char* ws = (char*)d_ws;
    size_t off = 0;
    __bf16* u  = (__bf16*)(ws + off); off += (size_t)M1 * DH * 2;   // 64 MiB
    __bf16* bT = (__bf16*)(ws + off); off += (size_t)DI * DH * 2;   // 2 MiB
    __bf16* cT = (__bf16*)(ws + off); off += (size_t)DH * DO * 2;   // 2 MiB
    if (ws_size < off) return;

    // scratch inside d_out (dead before gemm2 writes y)
    __bf16* xbf = (__bf16*)d_out;
    float*  E   = (float*)((char*)d_out + (size_t)M1 * DI * 2);
    float*  Cc  = E + (size_t)BS * NC * DH;

    conv_bf16_kernel<<<2048, 256, 0, stream>>>(x, xbf, (M1 * DI) / 8);
    transp_conv_kernel<<<dim3(DI / 32, DH / 32), 256, 0, stream>>>(b, bT, DI, DH);
    transp_conv_kernel<<<dim3(DH / 32, DO / 32), 256, 0, stream>>>(c, cT, DH, DO);
    // u = bf16(x @ b)
    gemm256_kernel<0><<<dim3(M1 / 256, DH / 256), 512, 0, stream>>>(xbf, bT, u, nullptr, M1, DH, DI);
    // chunked diagonal linear scan over T (in place on u)
    scan1_kernel<<<(BS * NC * (DH / 4)) / 256, 256, 0, stream>>>(u, a, E);
    scan2_kernel<<<(BS * DH) / 256, 256, 0, stream>>>(E, a, Cc);
    scan3_kernel<<<(BS * NC * (DH / 4)) / 256, 256, 0, stream>>>(u, a, Cc);
    // y = hs @ c
    gemm256_kernel<1><<<dim3(M1 / 256, DO / 256), 512, 0, stream>>>(u, cT, nullptr, y, M1, DO, DH);
}